// Round 16
// baseline (683.688 us; speedup 1.0000x reference)
//
#include <hip/hip_runtime.h>

// ---------- constants ----------
#define BB   64      // batch
#define TT   256     // seq len
#define EE   300     // embed dim
#define EP   320     // padded embed dim (mult of 32)
#define HH   256     // hidden per direction
#define ZN   1024    // 4*HH
#define KK   12      // tags
#define TAG_START 10
#define TAG_STOP  11
#define NEGV -10000.0f

// workspace layout (bytes)
#define OFF_XPAD  0ull                              // (unused after gather fusion)
#define OFF_WIH   10485760ull                       // [2048][320] bf16
#define OFF_ZX    11796480ull                       // [16384][2][256][4] bf16 (bias folded, gate-interleaved)
#define OFF_HF    78905344ull                       // [257][64][256] bf16
#define OFF_HB    87326720ull                       // [257][64][256] bf16
#define OFF_BIAS  95748096ull                       // [2][1024] f32
#define OFF_WOUT  95756288ull                       // [16][512] bf16
#define OFF_FEATS 95772672ull                       // [64][256][12] f32; whh_str borrows this
#define WS_NEED   96561152ull

typedef __attribute__((ext_vector_type(8))) short short8;
typedef __attribute__((ext_vector_type(4))) float f32x4;
typedef __attribute__((ext_vector_type(2))) float f32x2;
typedef __attribute__((ext_vector_type(4))) unsigned short u16x4;
typedef __attribute__((ext_vector_type(2))) unsigned short u16x2;

__device__ __forceinline__ unsigned short f2bf(float f) {
    unsigned x; __builtin_memcpy(&x, &f, 4);
    x += 0x7fffu + ((x >> 16) & 1u);
    return (unsigned short)(x >> 16);
}
__device__ __forceinline__ float bf2f(unsigned short u) {
    unsigned x = ((unsigned)u) << 16;
    float f; __builtin_memcpy(&f, &x, 4);
    return f;
}
__device__ __forceinline__ float rcpf_(float x) { return __builtin_amdgcn_rcpf(x); }
__device__ __forceinline__ float sigmoidf_(float x) {
    return rcpf_(1.0f + __expf(-x));          // v_rcp approx: err ~1e-5 << bf16 rounding
}
__device__ __forceinline__ float tanhf_(float x) {
    float e = __expf(-2.0f * fabsf(x));
    float r = (1.0f - e) * rcpf_(1.0f + e);
    return copysignf(r, x);
}

// lgkm-only workgroup barrier: orders LDS traffic without draining vmcnt(0),
// so the fire-and-forget global hist stores never put their ack on the step
// path. Compiler still auto-inserts vmcnt waits before any USE of global
// loads (zxv/wg6/wg7). sched_barrier pins code motion (guide rule #18).
__device__ __forceinline__ void lds_barrier() {
    __builtin_amdgcn_sched_barrier(0);
    asm volatile("s_waitcnt lgkmcnt(0)" ::: "memory");
    __builtin_amdgcn_s_barrier();
    __builtin_amdgcn_sched_barrier(0);
}

// ---------- 2. weight prep ----------
__global__ __launch_bounds__(256) void prep_kernel(
    const float* __restrict__ wih_f, const float* __restrict__ wih_b,
    const float* __restrict__ bih_f, const float* __restrict__ bhh_f,
    const float* __restrict__ bih_b, const float* __restrict__ bhh_b,
    const float* __restrict__ wout,
    const float* __restrict__ whh_f, const float* __restrict__ whh_b,
    unsigned short* __restrict__ wih_pad, float* __restrict__ bias,
    unsigned short* __restrict__ wout_pad, unsigned short* __restrict__ whh_str)
{
    int i = blockIdx.x * 256 + threadIdx.x;
    if (i < 2048 * EP) {                       // W_ih pad+cvt, [2048][320]
        int rr = i / EP, c = i - rr * EP;
        int dir = rr >> 10, r = rr & 1023;
        const float* w = dir ? wih_b : wih_f;
        wih_pad[i] = (c < EE) ? f2bf(w[r * EE + c]) : (unsigned short)0;
        return;
    }
    i -= 2048 * EP;
    if (i < 2 * ZN) {                          // bias = b_ih + b_hh
        int dir = i >> 10, z = i & 1023;
        bias[i] = dir ? (bih_b[z] + bhh_b[z]) : (bih_f[z] + bhh_f[z]);
        return;
    }
    i -= 2 * ZN;
    if (i < 16 * 512) {                        // W_out pad to [16][512] bf16
        int r = i >> 9, c = i & 511;
        wout_pad[i] = (r < KK) ? f2bf(wout[r * 512 + c]) : (unsigned short)0;
        return;
    }
    i -= 16 * 512;
    if (i < 2 * 1024 * 64) {                   // whh_str[dir][zrow][k 192..255] bf16 (kt 6,7)
        int dir = i >> 16, rem = i & 65535;
        int zr = rem >> 6, kc = rem & 63;
        const float* w = dir ? whh_b : whh_f;
        whh_str[i] = f2bf(w[(size_t)zr * 256 + 192 + kc]);
    }
}

// ---------- 3. fused gather + input GEMM: z_x = embed[sent] @ W_ih^T + bias ----------
// zx element layout: [row=t*64+b][dir][hc][gate]  (gate innermost)
// 64(M) x 256(N) tiles, 2048 blocks (R15 geometry, measured good).
// A-operand now gathered DIRECTLY from embed (f32 -> bf16 in-register):
// removes gather_kernel + the 10MB xpad write / 10MB read round-trip.
// Token-row pointers resolved once per lane (4 scalar sent loads, hoisted).
// Only kk==9 (cols 288..319) needs the EE=300 tail: lk==0 full 8, lk==1
// low-4 only, lk>=2 all zero -> no out-of-bounds loads.
__global__ __launch_bounds__(256, 4) void gemm_zx(
    const int* __restrict__ sent, const float* __restrict__ embed,
    const unsigned short* __restrict__ wih_pad,
    const float* __restrict__ bias,
    unsigned short* __restrict__ zx)
{
    int bid = blockIdx.x;
    int tm = bid & 255, tn2 = bid >> 8;        // 256 x 8 tiles of 64x256
    int lane = threadIdx.x & 63, w = threadIdx.x >> 6;
    int lm = lane & 15, lk = lane >> 4;
    int n0 = tn2 * 256 + w * 64;

    // resolve this lane's 4 A-row pointers (row = t*64+b -> token)
    const float* arow[4];
#pragma unroll
    for (int m = 0; m < 4; m++) {
        int row = tm * 64 + m * 16 + lm;
        int t = row >> 6, b = row & 63;
        arow[m] = embed + (size_t)sent[b * TT + t] * EE;
    }

    f32x4 acc[4][4];                           // [m][f]
#pragma unroll
    for (int m = 0; m < 4; m++)
#pragma unroll
        for (int f = 0; f < 4; f++) acc[m][f] = (f32x4){0.f, 0.f, 0.f, 0.f};

#pragma unroll
    for (int kk = 0; kk < 10; kk++) {
        short8 af[4], bf[4];
#pragma unroll
        for (int m = 0; m < 4; m++) {
            const float* src = arow[m] + kk * 32 + lk * 8;
            short8 v = (short8){0, 0, 0, 0, 0, 0, 0, 0};
            if (kk < 9) {
                f32x4 lo = *(const f32x4*)src;
                f32x4 hi = *(const f32x4*)(src + 4);
#pragma unroll
                for (int e = 0; e < 4; e++) { v[e] = (short)f2bf(lo[e]); v[4 + e] = (short)f2bf(hi[e]); }
            } else if (lk == 0) {              // cols 288..295: all valid
                f32x4 lo = *(const f32x4*)src;
                f32x4 hi = *(const f32x4*)(src + 4);
#pragma unroll
                for (int e = 0; e < 4; e++) { v[e] = (short)f2bf(lo[e]); v[4 + e] = (short)f2bf(hi[e]); }
            } else if (lk == 1) {              // cols 296..303: low 4 valid (296-299)
                f32x4 lo = *(const f32x4*)src;
#pragma unroll
                for (int e = 0; e < 4; e++) v[e] = (short)f2bf(lo[e]);
            }                                  // lk>=2: cols >=304, all zero
            af[m] = v;
        }
#pragma unroll
        for (int f = 0; f < 4; f++)
            bf[f] = *(const short8*)(wih_pad + (size_t)(n0 + f * 16 + lm) * EP + kk * 32 + lk * 8);
#pragma unroll
        for (int m = 0; m < 4; m++)
#pragma unroll
            for (int f = 0; f < 4; f++)
                acc[m][f] = __builtin_amdgcn_mfma_f32_16x16x32_bf16(af[m], bf[f], acc[m][f], 0, 0, 0);
    }

#pragma unroll
    for (int f = 0; f < 4; f++) {
        int zc = n0 + f * 16 + lm;             // 0..2047
        int dirz = zc >> 10, rem = zc & 1023, g = rem >> 8, hc = rem & 255;
        float bv = bias[zc];
#pragma unroll
        for (int m = 0; m < 4; m++)
#pragma unroll
            for (int r = 0; r < 4; r++) {
                int row = tm * 64 + m * 16 + lk * 4 + r;
                zx[(size_t)row * 2048 + dirz * 1024 + hc * 4 + g] = f2bf(acc[m][f][r] + bv);
            }
    }
}

// ---------- 4. recurrent LSTM: 32 blocks (dir x 16 batch-groups of 4) ----------
// R13/R15 config (measured 479us): single lgkm barrier, double-buffered hbuf,
// wave-local zlds. W_hh homes: kt0-3 -> 32 frags AGPR (128), kt4-5 -> LDS
// (128KB), kt6-7 streamed per pass from L2-hot slice [dir][1024][64].
__global__ __launch_bounds__(512)
__attribute__((amdgpu_waves_per_eu(2, 2)))
void lstm_rec(
    const unsigned short* __restrict__ zx,
    const float* __restrict__ whh_f, const float* __restrict__ whh_b,
    const unsigned short* __restrict__ whh_str,
    const float* __restrict__ h0, const float* __restrict__ c0,
    unsigned short* __restrict__ hf_hist, unsigned short* __restrict__ hb_hist)
{
    const int bid = blockIdx.x;
    const int dir = bid & 1, bg = bid >> 1;      // batch group: rows bg*4 .. bg*4+3
    const int tid = threadIdx.x;
    const int w = tid >> 6, lane = tid & 63;
    const int lm = lane & 15, lk = lane >> 4;

    __shared__ __align__(16) unsigned char wlds[128 * 1024];   // W_hh kt=4,5 frags
    __shared__ __align__(16) unsigned char hbuf[2][8192];      // h frags, double-buffered
    __shared__ __align__(16) float zlds[4 * 4 * 256];          // [g][b][hc ^ (b*8)] f32

    const float* whh = dir ? whh_b : whh_f;
    unsigned short* hist = dir ? hb_hist : hf_hist;
    const unsigned short* wstr = whh_str + dir * 65536;

    // ---- init: W_hh kt 0..3 -> regs, kt 4..5 -> LDS (frag order) ----
    short8 wreg[32];
#pragma unroll
    for (int tau = 0; tau < 8; tau++) {
        const int zr = (tau >> 1) * 256 + w * 32 + (tau & 1) * 16 + lm;
#pragma unroll
        for (int kt = 0; kt < 6; kt++) {
            const float* s = whh + (size_t)zr * 256 + kt * 32 + lk * 8;
            f32x4 lo = *(const f32x4*)s;
            f32x4 hi = *(const f32x4*)(s + 4);
            short8 f;
#pragma unroll
            for (int e = 0; e < 4; e++) { f[e] = (short)f2bf(lo[e]); f[4 + e] = (short)f2bf(hi[e]); }
            if (kt < 4) wreg[tau * 4 + kt] = f;
            else *(short8*)(wlds + (size_t)(((w * 2 + (kt - 4)) * 8 + tau) * 64 + lane) * 16) = f;
        }
    }

    // ---- gate-phase lane identity ----
    const int gb = tid & 3;                      // local batch row 0..3
    const int hc0 = (tid >> 2) * 2;              // h-col pair base (wave-local range)
    const int B = bg * 4 + gb;                   // global batch row
    // frag-order byte offset for h[b=gb][hc] in an hbuf buffer:
    const int hoff = (hc0 >> 5) * 1024 + ((hc0 >> 3) & 3) * 256 + gb * 16 + (hc0 & 7) * 2;

    // ---- init: zero BOTH hbufs, then h0 (valid rows), c0 -> regs ----
    *(uint4*)(hbuf[0] + tid * 16) = (uint4){0u, 0u, 0u, 0u};
    *(uint4*)(hbuf[1] + tid * 16) = (uint4){0u, 0u, 0u, 0u};
    __syncthreads();
    f32x2 cv = *(const f32x2*)(c0 + ((size_t)dir * BB + B) * HH + hc0);
    f32x2 hv0 = *(const f32x2*)(h0 + ((size_t)dir * BB + B) * HH + hc0);
    float c0r = cv[0], c1r = cv[1];
    *(u16x2*)(hbuf[0] + hoff) = (u16x2){f2bf(hv0[0]), f2bf(hv0[1])};
    __syncthreads();

    int cur = 0;
#pragma unroll 1
    for (int s = 0; s < TT; s++) {
        const int t = dir ? (TT - 1 - s) : s;
        const int wslot = dir ? t : (s + 1);

        // prefetch z_x for this lane's gate-phase work: [hc0..hc0+1] x 4 gates = 16B
        short8 zxv = *(const short8*)(zx + ((size_t)t * BB + B) * 2048 + dir * ZN + hc0 * 4);

        const unsigned char* rb = hbuf[cur];
        unsigned char* wb = hbuf[cur ^ 1];

#pragma unroll
        for (int pass = 0; pass < 2; pass++) {
            // streamed W frags for kt 6,7 (L2-hot), this pass's taus
            short8 wg6[4], wg7[4];
#pragma unroll
            for (int g = 0; g < 4; g++) {
                const int zr = g * 256 + w * 32 + pass * 16 + lm;
                wg6[g] = *(const short8*)(wstr + (size_t)zr * 64 + lk * 8);
                wg7[g] = *(const short8*)(wstr + (size_t)zr * 64 + 32 + lk * 8);
            }

            f32x4 acc[4];
#pragma unroll
            for (int g = 0; g < 4; g++) acc[g] = (f32x4){0.f, 0.f, 0.f, 0.f};

#pragma unroll
            for (int kt = 0; kt < 8; kt++) {
                short8 hb = *(const short8*)(rb + kt * 1024 + lane * 16);
#pragma unroll
                for (int g = 0; g < 4; g++) {
                    const int tau = g * 2 + pass;
                    short8 a;
                    if (kt < 4)       a = wreg[tau * 4 + kt];
                    else if (kt < 6)  a = *(const short8*)(wlds + (size_t)(((w * 2 + (kt - 4)) * 8 + tau) * 64 + lane) * 16);
                    else if (kt == 6) a = wg6[g];
                    else              a = wg7[g];
                    acc[g] = __builtin_amdgcn_mfma_f32_16x16x32_bf16(a, hb, acc[g], 0, 0, 0);
                }
            }

            // scatter z to zlds (valid batch columns only; XOR-swizzled by b).
            // WAVE-LOCAL: wave w writes cols w*32+..; its own gate lanes read them.
            if (lm < 4) {
                const int hcb = w * 32 + pass * 16 + lk * 4;
#pragma unroll
                for (int g = 0; g < 4; g++)
                    *(f32x4*)&zlds[(g * 4 + lm) * 256 + (hcb ^ (lm * 8))] = acc[g];
            }
        }
        // NO barrier here: scatter->gate-read is same-wave, in-order DS.

        // ---- gate phase: 2 h-values per lane ----
        f32x2 zrr[4];
#pragma unroll
        for (int g = 0; g < 4; g++)
            zrr[g] = *(const f32x2*)&zlds[(g * 4 + gb) * 256 + (hc0 ^ (gb * 8))];

        u16x2 hv;
        {
            float zi = zrr[0][0] + bf2f((unsigned short)zxv[0]);
            float zf = zrr[1][0] + bf2f((unsigned short)zxv[1]);
            float zg = zrr[2][0] + bf2f((unsigned short)zxv[2]);
            float zo = zrr[3][0] + bf2f((unsigned short)zxv[3]);
            float cc = sigmoidf_(zf) * c0r + sigmoidf_(zi) * tanhf_(zg);
            c0r = cc;
            hv[0] = f2bf(sigmoidf_(zo) * tanhf_(cc));
        }
        {
            float zi = zrr[0][1] + bf2f((unsigned short)zxv[4]);
            float zf = zrr[1][1] + bf2f((unsigned short)zxv[5]);
            float zg = zrr[2][1] + bf2f((unsigned short)zxv[6]);
            float zo = zrr[3][1] + bf2f((unsigned short)zxv[7]);
            float cc = sigmoidf_(zf) * c1r + sigmoidf_(zi) * tanhf_(zg);
            c1r = cc;
            hv[1] = f2bf(sigmoidf_(zo) * tanhf_(cc));
        }
        *(u16x2*)(wb + hoff) = hv;               // next step's h (other buffer)
        *(u16x2*)(hist + ((size_t)wslot * BB + B) * HH + hc0) = hv;  // fire-and-forget

        lds_barrier();     // single barrier: wb visible; rb reads drained (lgkm only)
        cur ^= 1;
    }
}

// ---------- 5. feats = concat(hf,hb) @ W_out^T + b_out ----------
__global__ __launch_bounds__(256) void feats_kernel(
    const unsigned short* __restrict__ hf_hist, const unsigned short* __restrict__ hb_hist,
    const unsigned short* __restrict__ wout_pad, const float* __restrict__ b_out,
    float* __restrict__ feats)
{
    const int tid = threadIdx.x, lane = tid & 63, w = tid >> 6;
    const int lm = lane & 15, lk = lane >> 4;
    const int r0 = blockIdx.x * 64;             // rows r = t*64+b

    __shared__ float red[4][64][16];

    const unsigned short* hsrc = (w < 2) ? (hf_hist + BB * HH) : hb_hist;
    const int kb = (w & 1) * 128;

    f32x4 acc[4];
#pragma unroll
    for (int m = 0; m < 4; m++) acc[m] = (f32x4){0.f, 0.f, 0.f, 0.f};

#pragma unroll
    for (int kk = 0; kk < 4; kk++) {
        short8 bf = *(const short8*)(wout_pad + (size_t)lm * 512 + w * 128 + kk * 32 + lk * 8);
#pragma unroll
        for (int m = 0; m < 4; m++) {
            short8 a = *(const short8*)(hsrc + (size_t)(r0 + m * 16 + lm) * HH + kb + kk * 32 + lk * 8);
            acc[m] = __builtin_amdgcn_mfma_f32_16x16x32_bf16(a, bf, acc[m], 0, 0, 0);
        }
    }
#pragma unroll
    for (int m = 0; m < 4; m++)
#pragma unroll
        for (int r = 0; r < 4; r++)
            red[w][m * 16 + lk * 4 + r][lm] = acc[m][r];
    __syncthreads();

#pragma unroll
    for (int q = 0; q < 4; q++) {
        int e = tid + q * 256;
        int row = e >> 4, col = e & 15;
        if (col < KK) {
            float v = red[0][row][col] + red[1][row][col] + red[2][row][col] + red[3][row][col]
                      + b_out[col];
            int gr = r0 + row, t = gr >> 6, bb = gr & 63;
            feats[(size_t)bb * TT * KK + t * KK + col] = v;
        }
    }
}

// ---------- 6. Viterbi decode (wave per batch) ----------
__global__ __launch_bounds__(256) void viterbi_kernel(
    const float* __restrict__ feats, const float* __restrict__ trans,
    float* __restrict__ out)
{
    __shared__ float fl[4][TT * KK];
    __shared__ unsigned char bp[4][TT][KK];
    const int tid = threadIdx.x, lane = tid & 63, v = tid >> 6;
    const int b = blockIdx.x * 4 + v;

    for (int i = lane; i < TT * KK; i += 64) fl[v][i] = feats[(size_t)b * TT * KK + i];
    __syncthreads();

    float trow[12] = {0};
    float tstop = 0.f;
    if (lane < KK) {
#pragma unroll
        for (int p = 0; p < KK; p++) trow[p] = trans[lane * KK + p];
        tstop = trans[TAG_STOP * KK + lane];
    }
    float fv = (lane == TAG_START) ? 0.0f : NEGV;

    for (int t = 0; t < TT; t++) {
        float best = -3.0e38f; int arg = 0;
#pragma unroll
        for (int p = 0; p < KK; p++) {
            float sc = __shfl(fv, p, 64) + trow[p];
            if (sc > best) { best = sc; arg = p; }
        }
        if (lane < KK) {
            bp[v][t][lane] = (unsigned char)arg;
            fv = best + fl[v][t * KK + lane];
        }
    }

    float term = fv + tstop;
    float best = -3.0e38f; int arg = 0;
#pragma unroll
    for (int p = 0; p < KK; p++) {
        float sc = __shfl(term, p, 64);
        if (sc > best) { best = sc; arg = p; }
    }
    if (lane == 0) {
        out[b] = best;
        int tag = arg;
        for (int t = TT - 1; t >= 0; t--) {
            out[BB + (size_t)b * TT + t] = (float)tag;
            if (t > 0) tag = bp[v][t][tag];
        }
    }
}

// ---------- launch ----------
extern "C" void kernel_launch(void* const* d_in, const int* in_sizes, int n_in,
                              void* d_out, int out_size, void* d_ws, size_t ws_size,
                              hipStream_t stream)
{
    (void)in_sizes; (void)n_in; (void)out_size;
    const int*   sent  = (const int*)d_in[0];
    const float* embed = (const float*)d_in[1];
    const float* wih_f = (const float*)d_in[2];
    const float* whh_f = (const float*)d_in[3];
    const float* bih_f = (const float*)d_in[4];
    const float* bhh_f = (const float*)d_in[5];
    const float* wih_b = (const float*)d_in[6];
    const float* whh_b = (const float*)d_in[7];
    const float* bih_b = (const float*)d_in[8];
    const float* bhh_b = (const float*)d_in[9];
    const float* wout  = (const float*)d_in[10];
    const float* bout  = (const float*)d_in[11];
    const float* trans = (const float*)d_in[12];
    const float* h0    = (const float*)d_in[13];
    const float* c0    = (const float*)d_in[14];
    float* out = (float*)d_out;

    if (ws_size < WS_NEED) return;

    char* ws = (char*)d_ws;
    unsigned short* wih_pad  = (unsigned short*)(ws + OFF_WIH);
    unsigned short* zx       = (unsigned short*)(ws + OFF_ZX);
    unsigned short* hf_hist  = (unsigned short*)(ws + OFF_HF);
    unsigned short* hb_hist  = (unsigned short*)(ws + OFF_HB);
    float*          bias     = (float*)(ws + OFF_BIAS);
    unsigned short* wout_pad = (unsigned short*)(ws + OFF_WOUT);
    float*          feats    = (float*)(ws + OFF_FEATS);
    unsigned short* whh_str  = (unsigned short*)(ws + OFF_FEATS);  // overlaps feats: read before feats written

    prep_kernel<<<(2048 * EP + 2 * ZN + 16 * 512 + 2 * 1024 * 64 + 255) / 256, 256, 0, stream>>>(
        wih_f, wih_b, bih_f, bhh_f, bih_b, bhh_b, wout, whh_f, whh_b,
        wih_pad, bias, wout_pad, whh_str);
    gemm_zx<<<2048, 256, 0, stream>>>(sent, embed, wih_pad, bias, zx);
    lstm_rec<<<32, 512, 0, stream>>>(zx, whh_f, whh_b, whh_str, h0, c0, hf_hist, hb_hist);
    feats_kernel<<<256, 256, 0, stream>>>(hf_hist, hb_hist, wout_pad, bout, feats);
    viterbi_kernel<<<16, 256, 0, stream>>>(feats, trans, out);
}

// Round 17
// 667.649 us; speedup vs baseline: 1.0240x; 1.0240x over previous
//
#include <hip/hip_runtime.h>

// ---------- constants ----------
#define BB   64      // batch
#define TT   256     // seq len
#define EE   300     // embed dim
#define EP   320     // padded embed dim (mult of 32)
#define HH   256     // hidden per direction
#define ZN   1024    // 4*HH
#define KK   12      // tags
#define TAG_START 10
#define TAG_STOP  11
#define NEGV -10000.0f

// workspace layout (bytes)
#define OFF_XPAD  0ull                              // [16384][320] bf16
#define OFF_WIH   10485760ull                       // [2048][320] bf16
#define OFF_ZX    11796480ull                       // [16384][2][256][4] bf16 (bias folded, gate-interleaved)
#define OFF_HF    78905344ull                       // [257][64][256] bf16
#define OFF_HB    87326720ull                       // [257][64][256] bf16
#define OFF_BIAS  95748096ull                       // [2][1024] f32
#define OFF_WOUT  95756288ull                       // [16][512] bf16
#define OFF_FEATS 95772672ull                       // [64][256][12] f32; whh_str borrows this
#define WS_NEED   96561152ull

typedef __attribute__((ext_vector_type(8))) short short8;
typedef __attribute__((ext_vector_type(4))) float f32x4;
typedef __attribute__((ext_vector_type(2))) float f32x2;
typedef __attribute__((ext_vector_type(4))) unsigned short u16x4;
typedef __attribute__((ext_vector_type(2))) unsigned short u16x2;

__device__ __forceinline__ unsigned short f2bf(float f) {
    unsigned x; __builtin_memcpy(&x, &f, 4);
    x += 0x7fffu + ((x >> 16) & 1u);
    return (unsigned short)(x >> 16);
}
__device__ __forceinline__ float bf2f(unsigned short u) {
    unsigned x = ((unsigned)u) << 16;
    float f; __builtin_memcpy(&f, &x, 4);
    return f;
}
__device__ __forceinline__ float rcpf_(float x) { return __builtin_amdgcn_rcpf(x); }
__device__ __forceinline__ float sigmoidf_(float x) {
    return rcpf_(1.0f + __expf(-x));          // v_rcp approx: err ~1e-5 << bf16 rounding
}
__device__ __forceinline__ float tanhf_(float x) {
    float e = __expf(-2.0f * fabsf(x));
    float r = (1.0f - e) * rcpf_(1.0f + e);
    return copysignf(r, x);
}

// lgkm-only workgroup barrier: orders LDS traffic without draining vmcnt(0),
// so the fire-and-forget global hist stores never put their ack on the step
// path. sched_barrier pins code motion (guide rule #18).
__device__ __forceinline__ void lds_barrier() {
    __builtin_amdgcn_sched_barrier(0);
    asm volatile("s_waitcnt lgkmcnt(0)" ::: "memory");
    __builtin_amdgcn_s_barrier();
    __builtin_amdgcn_sched_barrier(0);
}

// ---------- 1. embedding gather + pad (v2: 2048 blocks, vectorized) ----------
// 8 rows/block; f32x4 loads -> u16x4 stores. vector v covers cols v*4..v*4+3:
// v<75 fully valid (EE=300), v>=75 zero-pad (cols 300..319).
__global__ __launch_bounds__(256) void gather_kernel(
    const int* __restrict__ sent, const float* __restrict__ embed,
    unsigned short* __restrict__ xpad)
{
    const int tid = threadIdx.x;
    const int r0 = blockIdx.x * 8;
#pragma unroll
    for (int k = 0; k < 3; k++) {
        int e = tid + k * 256;                 // 0..639 (8 rows x 80 vectors)
        if (e >= 640) break;
        int ri = e / 80, v = e - ri * 80;
        int r = r0 + ri;                       // r = t*64 + b
        int t = r >> 6, b = r & 63;
        u16x4 outv = (u16x4){0, 0, 0, 0};
        if (v < 75) {
            const float* src = embed + (size_t)sent[b * TT + t] * EE + v * 4;
            f32x4 f = *(const f32x4*)src;
#pragma unroll
            for (int j = 0; j < 4; j++) outv[j] = f2bf(f[j]);
        }
        *(u16x4*)(xpad + (size_t)r * EP + v * 4) = outv;
    }
}

// ---------- 2. weight prep ----------
__global__ __launch_bounds__(256) void prep_kernel(
    const float* __restrict__ wih_f, const float* __restrict__ wih_b,
    const float* __restrict__ bih_f, const float* __restrict__ bhh_f,
    const float* __restrict__ bih_b, const float* __restrict__ bhh_b,
    const float* __restrict__ wout,
    const float* __restrict__ whh_f, const float* __restrict__ whh_b,
    unsigned short* __restrict__ wih_pad, float* __restrict__ bias,
    unsigned short* __restrict__ wout_pad, unsigned short* __restrict__ whh_str)
{
    int i = blockIdx.x * 256 + threadIdx.x;
    if (i < 2048 * EP) {                       // W_ih pad+cvt, [2048][320]
        int rr = i / EP, c = i - rr * EP;
        int dir = rr >> 10, r = rr & 1023;
        const float* w = dir ? wih_b : wih_f;
        wih_pad[i] = (c < EE) ? f2bf(w[r * EE + c]) : (unsigned short)0;
        return;
    }
    i -= 2048 * EP;
    if (i < 2 * ZN) {                          // bias = b_ih + b_hh
        int dir = i >> 10, z = i & 1023;
        bias[i] = dir ? (bih_b[z] + bhh_b[z]) : (bih_f[z] + bhh_f[z]);
        return;
    }
    i -= 2 * ZN;
    if (i < 16 * 512) {                        // W_out pad to [16][512] bf16
        int r = i >> 9, c = i & 511;
        wout_pad[i] = (r < KK) ? f2bf(wout[r * 512 + c]) : (unsigned short)0;
        return;
    }
    i -= 16 * 512;
    if (i < 2 * 1024 * 64) {                   // whh_str[dir][zrow][k 192..255] bf16 (kt 6,7)
        int dir = i >> 16, rem = i & 65535;
        int zr = rem >> 6, kc = rem & 63;
        const float* w = dir ? whh_b : whh_f;
        whh_str[i] = f2bf(w[(size_t)zr * 256 + 192 + kc]);
    }
}

// ---------- 3. input GEMM: z_x = x @ W_ih^T + bias, gate-interleaved bf16 out ----------
// zx element layout: [row=t*64+b][dir][hc][gate]  (gate innermost)
// 64(M) x 256(N) tiles, 2048 blocks (R15 geometry, measured good).
__global__ __launch_bounds__(256, 4) void gemm_zx(
    const unsigned short* __restrict__ xpad,
    const unsigned short* __restrict__ wih_pad,
    const float* __restrict__ bias,
    unsigned short* __restrict__ zx)
{
    int bid = blockIdx.x;
    int tm = bid & 255, tn2 = bid >> 8;        // 256 x 8 tiles of 64x256
    int lane = threadIdx.x & 63, w = threadIdx.x >> 6;
    int lm = lane & 15, lk = lane >> 4;
    int n0 = tn2 * 256 + w * 64;

    f32x4 acc[4][4];                           // [m][f]
#pragma unroll
    for (int m = 0; m < 4; m++)
#pragma unroll
        for (int f = 0; f < 4; f++) acc[m][f] = (f32x4){0.f, 0.f, 0.f, 0.f};

#pragma unroll
    for (int kk = 0; kk < 10; kk++) {
        short8 af[4], bf[4];
#pragma unroll
        for (int m = 0; m < 4; m++)
            af[m] = *(const short8*)(xpad + (size_t)(tm * 64 + m * 16 + lm) * EP + kk * 32 + lk * 8);
#pragma unroll
        for (int f = 0; f < 4; f++)
            bf[f] = *(const short8*)(wih_pad + (size_t)(n0 + f * 16 + lm) * EP + kk * 32 + lk * 8);
#pragma unroll
        for (int m = 0; m < 4; m++)
#pragma unroll
            for (int f = 0; f < 4; f++)
                acc[m][f] = __builtin_amdgcn_mfma_f32_16x16x32_bf16(af[m], bf[f], acc[m][f], 0, 0, 0);
    }

#pragma unroll
    for (int f = 0; f < 4; f++) {
        int zc = n0 + f * 16 + lm;             // 0..2047
        int dirz = zc >> 10, rem = zc & 1023, g = rem >> 8, hc = rem & 255;
        float bv = bias[zc];
#pragma unroll
        for (int m = 0; m < 4; m++)
#pragma unroll
            for (int r = 0; r < 4; r++) {
                int row = tm * 64 + m * 16 + lk * 4 + r;
                zx[(size_t)row * 2048 + dirz * 1024 + hc * 4 + g] = f2bf(acc[m][f][r] + bv);
            }
    }
}

// ---------- 4. recurrent LSTM: 32 blocks (dir x 16 batch-groups of 4) ----------
// R13/R15 config (measured 479us): single lgkm barrier, double-buffered hbuf,
// wave-local zlds. W_hh homes: kt0-3 -> 32 frags AGPR (128), kt4-5 -> LDS
// (128KB), kt6-7 streamed per pass from L2-hot slice [dir][1024][64].
__global__ __launch_bounds__(512)
__attribute__((amdgpu_waves_per_eu(2, 2)))
void lstm_rec(
    const unsigned short* __restrict__ zx,
    const float* __restrict__ whh_f, const float* __restrict__ whh_b,
    const unsigned short* __restrict__ whh_str,
    const float* __restrict__ h0, const float* __restrict__ c0,
    unsigned short* __restrict__ hf_hist, unsigned short* __restrict__ hb_hist)
{
    const int bid = blockIdx.x;
    const int dir = bid & 1, bg = bid >> 1;      // batch group: rows bg*4 .. bg*4+3
    const int tid = threadIdx.x;
    const int w = tid >> 6, lane = tid & 63;
    const int lm = lane & 15, lk = lane >> 4;

    __shared__ __align__(16) unsigned char wlds[128 * 1024];   // W_hh kt=4,5 frags
    __shared__ __align__(16) unsigned char hbuf[2][8192];      // h frags, double-buffered
    __shared__ __align__(16) float zlds[4 * 4 * 256];          // [g][b][hc ^ (b*8)] f32

    const float* whh = dir ? whh_b : whh_f;
    unsigned short* hist = dir ? hb_hist : hf_hist;
    const unsigned short* wstr = whh_str + dir * 65536;

    // ---- init: W_hh kt 0..3 -> regs, kt 4..5 -> LDS (frag order) ----
    short8 wreg[32];
#pragma unroll
    for (int tau = 0; tau < 8; tau++) {
        const int zr = (tau >> 1) * 256 + w * 32 + (tau & 1) * 16 + lm;
#pragma unroll
        for (int kt = 0; kt < 6; kt++) {
            const float* s = whh + (size_t)zr * 256 + kt * 32 + lk * 8;
            f32x4 lo = *(const f32x4*)s;
            f32x4 hi = *(const f32x4*)(s + 4);
            short8 f;
#pragma unroll
            for (int e = 0; e < 4; e++) { f[e] = (short)f2bf(lo[e]); f[4 + e] = (short)f2bf(hi[e]); }
            if (kt < 4) wreg[tau * 4 + kt] = f;
            else *(short8*)(wlds + (size_t)(((w * 2 + (kt - 4)) * 8 + tau) * 64 + lane) * 16) = f;
        }
    }

    // ---- gate-phase lane identity ----
    const int gb = tid & 3;                      // local batch row 0..3
    const int hc0 = (tid >> 2) * 2;              // h-col pair base (wave-local range)
    const int B = bg * 4 + gb;                   // global batch row
    // frag-order byte offset for h[b=gb][hc] in an hbuf buffer:
    const int hoff = (hc0 >> 5) * 1024 + ((hc0 >> 3) & 3) * 256 + gb * 16 + (hc0 & 7) * 2;

    // ---- init: zero BOTH hbufs, then h0 (valid rows), c0 -> regs ----
    *(uint4*)(hbuf[0] + tid * 16) = (uint4){0u, 0u, 0u, 0u};
    *(uint4*)(hbuf[1] + tid * 16) = (uint4){0u, 0u, 0u, 0u};
    __syncthreads();
    f32x2 cv = *(const f32x2*)(c0 + ((size_t)dir * BB + B) * HH + hc0);
    f32x2 hv0 = *(const f32x2*)(h0 + ((size_t)dir * BB + B) * HH + hc0);
    float c0r = cv[0], c1r = cv[1];
    *(u16x2*)(hbuf[0] + hoff) = (u16x2){f2bf(hv0[0]), f2bf(hv0[1])};
    __syncthreads();

    int cur = 0;
#pragma unroll 1
    for (int s = 0; s < TT; s++) {
        const int t = dir ? (TT - 1 - s) : s;
        const int wslot = dir ? t : (s + 1);

        // prefetch z_x for this lane's gate-phase work: [hc0..hc0+1] x 4 gates = 16B
        short8 zxv = *(const short8*)(zx + ((size_t)t * BB + B) * 2048 + dir * ZN + hc0 * 4);

        const unsigned char* rb = hbuf[cur];
        unsigned char* wb = hbuf[cur ^ 1];

#pragma unroll
        for (int pass = 0; pass < 2; pass++) {
            // streamed W frags for kt 6,7 (L2-hot), this pass's taus
            short8 wg6[4], wg7[4];
#pragma unroll
            for (int g = 0; g < 4; g++) {
                const int zr = g * 256 + w * 32 + pass * 16 + lm;
                wg6[g] = *(const short8*)(wstr + (size_t)zr * 64 + lk * 8);
                wg7[g] = *(const short8*)(wstr + (size_t)zr * 64 + 32 + lk * 8);
            }

            f32x4 acc[4];
#pragma unroll
            for (int g = 0; g < 4; g++) acc[g] = (f32x4){0.f, 0.f, 0.f, 0.f};

#pragma unroll
            for (int kt = 0; kt < 8; kt++) {
                short8 hb = *(const short8*)(rb + kt * 1024 + lane * 16);
#pragma unroll
                for (int g = 0; g < 4; g++) {
                    const int tau = g * 2 + pass;
                    short8 a;
                    if (kt < 4)       a = wreg[tau * 4 + kt];
                    else if (kt < 6)  a = *(const short8*)(wlds + (size_t)(((w * 2 + (kt - 4)) * 8 + tau) * 64 + lane) * 16);
                    else if (kt == 6) a = wg6[g];
                    else              a = wg7[g];
                    acc[g] = __builtin_amdgcn_mfma_f32_16x16x32_bf16(a, hb, acc[g], 0, 0, 0);
                }
            }

            // scatter z to zlds (valid batch columns only; XOR-swizzled by b).
            // WAVE-LOCAL: wave w writes cols w*32+..; its own gate lanes read them.
            if (lm < 4) {
                const int hcb = w * 32 + pass * 16 + lk * 4;
#pragma unroll
                for (int g = 0; g < 4; g++)
                    *(f32x4*)&zlds[(g * 4 + lm) * 256 + (hcb ^ (lm * 8))] = acc[g];
            }
        }
        // NO barrier here: scatter->gate-read is same-wave, in-order DS.

        // ---- gate phase: 2 h-values per lane ----
        f32x2 zrr[4];
#pragma unroll
        for (int g = 0; g < 4; g++)
            zrr[g] = *(const f32x2*)&zlds[(g * 4 + gb) * 256 + (hc0 ^ (gb * 8))];

        u16x2 hv;
        {
            float zi = zrr[0][0] + bf2f((unsigned short)zxv[0]);
            float zf = zrr[1][0] + bf2f((unsigned short)zxv[1]);
            float zg = zrr[2][0] + bf2f((unsigned short)zxv[2]);
            float zo = zrr[3][0] + bf2f((unsigned short)zxv[3]);
            float cc = sigmoidf_(zf) * c0r + sigmoidf_(zi) * tanhf_(zg);
            c0r = cc;
            hv[0] = f2bf(sigmoidf_(zo) * tanhf_(cc));
        }
        {
            float zi = zrr[0][1] + bf2f((unsigned short)zxv[4]);
            float zf = zrr[1][1] + bf2f((unsigned short)zxv[5]);
            float zg = zrr[2][1] + bf2f((unsigned short)zxv[6]);
            float zo = zrr[3][1] + bf2f((unsigned short)zxv[7]);
            float cc = sigmoidf_(zf) * c1r + sigmoidf_(zi) * tanhf_(zg);
            c1r = cc;
            hv[1] = f2bf(sigmoidf_(zo) * tanhf_(cc));
        }
        *(u16x2*)(wb + hoff) = hv;               // next step's h (other buffer)
        *(u16x2*)(hist + ((size_t)wslot * BB + B) * HH + hc0) = hv;  // fire-and-forget

        lds_barrier();     // single barrier: wb visible; rb reads drained (lgkm only)
        cur ^= 1;
    }
}

// ---------- 5. feats = concat(hf,hb) @ W_out^T + b_out ----------
__global__ __launch_bounds__(256) void feats_kernel(
    const unsigned short* __restrict__ hf_hist, const unsigned short* __restrict__ hb_hist,
    const unsigned short* __restrict__ wout_pad, const float* __restrict__ b_out,
    float* __restrict__ feats)
{
    const int tid = threadIdx.x, lane = tid & 63, w = tid >> 6;
    const int lm = lane & 15, lk = lane >> 4;
    const int r0 = blockIdx.x * 64;             // rows r = t*64+b

    __shared__ float red[4][64][16];

    const unsigned short* hsrc = (w < 2) ? (hf_hist + BB * HH) : hb_hist;
    const int kb = (w & 1) * 128;

    f32x4 acc[4];
#pragma unroll
    for (int m = 0; m < 4; m++) acc[m] = (f32x4){0.f, 0.f, 0.f, 0.f};

#pragma unroll
    for (int kk = 0; kk < 4; kk++) {
        short8 bf = *(const short8*)(wout_pad + (size_t)lm * 512 + w * 128 + kk * 32 + lk * 8);
#pragma unroll
        for (int m = 0; m < 4; m++) {
            short8 a = *(const short8*)(hsrc + (size_t)(r0 + m * 16 + lm) * HH + kb + kk * 32 + lk * 8);
            acc[m] = __builtin_amdgcn_mfma_f32_16x16x32_bf16(a, bf, acc[m], 0, 0, 0);
        }
    }
#pragma unroll
    for (int m = 0; m < 4; m++)
#pragma unroll
        for (int r = 0; r < 4; r++)
            red[w][m * 16 + lk * 4 + r][lm] = acc[m][r];
    __syncthreads();

#pragma unroll
    for (int q = 0; q < 4; q++) {
        int e = tid + q * 256;
        int row = e >> 4, col = e & 15;
        if (col < KK) {
            float v = red[0][row][col] + red[1][row][col] + red[2][row][col] + red[3][row][col]
                      + b_out[col];
            int gr = r0 + row, t = gr >> 6, bb = gr & 63;
            feats[(size_t)bb * TT * KK + t * KK + col] = v;
        }
    }
}

// ---------- 6. Viterbi decode (wave per batch) ----------
__global__ __launch_bounds__(256) void viterbi_kernel(
    const float* __restrict__ feats, const float* __restrict__ trans,
    float* __restrict__ out)
{
    __shared__ float fl[4][TT * KK];
    __shared__ unsigned char bp[4][TT][KK];
    const int tid = threadIdx.x, lane = tid & 63, v = tid >> 6;
    const int b = blockIdx.x * 4 + v;

    for (int i = lane; i < TT * KK; i += 64) fl[v][i] = feats[(size_t)b * TT * KK + i];
    __syncthreads();

    float trow[12] = {0};
    float tstop = 0.f;
    if (lane < KK) {
#pragma unroll
        for (int p = 0; p < KK; p++) trow[p] = trans[lane * KK + p];
        tstop = trans[TAG_STOP * KK + lane];
    }
    float fv = (lane == TAG_START) ? 0.0f : NEGV;

    for (int t = 0; t < TT; t++) {
        float best = -3.0e38f; int arg = 0;
#pragma unroll
        for (int p = 0; p < KK; p++) {
            float sc = __shfl(fv, p, 64) + trow[p];
            if (sc > best) { best = sc; arg = p; }
        }
        if (lane < KK) {
            bp[v][t][lane] = (unsigned char)arg;
            fv = best + fl[v][t * KK + lane];
        }
    }

    float term = fv + tstop;
    float best = -3.0e38f; int arg = 0;
#pragma unroll
    for (int p = 0; p < KK; p++) {
        float sc = __shfl(term, p, 64);
        if (sc > best) { best = sc; arg = p; }
    }
    if (lane == 0) {
        out[b] = best;
        int tag = arg;
        for (int t = TT - 1; t >= 0; t--) {
            out[BB + (size_t)b * TT + t] = (float)tag;
            if (t > 0) tag = bp[v][t][tag];
        }
    }
}

// ---------- launch ----------
extern "C" void kernel_launch(void* const* d_in, const int* in_sizes, int n_in,
                              void* d_out, int out_size, void* d_ws, size_t ws_size,
                              hipStream_t stream)
{
    (void)in_sizes; (void)n_in; (void)out_size;
    const int*   sent  = (const int*)d_in[0];
    const float* embed = (const float*)d_in[1];
    const float* wih_f = (const float*)d_in[2];
    const float* whh_f = (const float*)d_in[3];
    const float* bih_f = (const float*)d_in[4];
    const float* bhh_f = (const float*)d_in[5];
    const float* wih_b = (const float*)d_in[6];
    const float* whh_b = (const float*)d_in[7];
    const float* bih_b = (const float*)d_in[8];
    const float* bhh_b = (const float*)d_in[9];
    const float* wout  = (const float*)d_in[10];
    const float* bout  = (const float*)d_in[11];
    const float* trans = (const float*)d_in[12];
    const float* h0    = (const float*)d_in[13];
    const float* c0    = (const float*)d_in[14];
    float* out = (float*)d_out;

    if (ws_size < WS_NEED) return;

    char* ws = (char*)d_ws;
    unsigned short* xpad     = (unsigned short*)(ws + OFF_XPAD);
    unsigned short* wih_pad  = (unsigned short*)(ws + OFF_WIH);
    unsigned short* zx       = (unsigned short*)(ws + OFF_ZX);
    unsigned short* hf_hist  = (unsigned short*)(ws + OFF_HF);
    unsigned short* hb_hist  = (unsigned short*)(ws + OFF_HB);
    float*          bias     = (float*)(ws + OFF_BIAS);
    unsigned short* wout_pad = (unsigned short*)(ws + OFF_WOUT);
    float*          feats    = (float*)(ws + OFF_FEATS);
    unsigned short* whh_str  = (unsigned short*)(ws + OFF_FEATS);  // overlaps feats: read before feats written

    gather_kernel<<<2048, 256, 0, stream>>>(sent, embed, xpad);
    prep_kernel<<<(2048 * EP + 2 * ZN + 16 * 512 + 2 * 1024 * 64 + 255) / 256, 256, 0, stream>>>(
        wih_f, wih_b, bih_f, bhh_f, bih_b, bhh_b, wout, whh_f, whh_b,
        wih_pad, bias, wout_pad, whh_str);
    gemm_zx<<<2048, 256, 0, stream>>>(xpad, wih_pad, bias, zx);
    lstm_rec<<<32, 512, 0, stream>>>(zx, whh_f, whh_b, whh_str, h0, c0, hf_hist, hb_hist);
    feats_kernel<<<256, 256, 0, stream>>>(hf_hist, hb_hist, wout_pad, bout, feats);
    viterbi_kernel<<<16, 256, 0, stream>>>(feats, trans, out);
}